// Round 7
// baseline (342.181 us; speedup 1.0000x reference)
//
#include <hip/hip_runtime.h>
#include <hip/hip_bf16.h>

#define Bsz 4
#define Cm 192
#define Lseq 4096
#define Din 384
#define Dst 16
#define NCk 128
#define CLk 32    // Lseq/NCk

typedef short s8v __attribute__((ext_vector_type(8)));
typedef float f4v __attribute__((ext_vector_type(4)));
typedef unsigned short ushort_t;

__device__ __forceinline__ unsigned int f2bf(float v) {
  unsigned int u = __float_as_uint(v);
  return (u + 0x7FFFu + ((u >> 16) & 1u)) >> 16;
}
__device__ __forceinline__ float bf2f(unsigned int h) {
  return __uint_as_float(h << 16);
}

// ======================= split-bf16 MFMA GEMM core =======================
#define KP 72

template<int K, int NMAX>
__device__ __forceinline__ void mfma_gemm64(
    const ushort_t* __restrict__ Ah, const ushort_t* __restrict__ Al, long arow0,
    const ushort_t* __restrict__ Bh, const ushort_t* __restrict__ Bl, int nbase,
    ushort_t* sAh, ushort_t* sAl, ushort_t* sBh, ushort_t* sBl,
    f4v acc[2][2]) {
  int t = threadIdx.x;
  int lane = t & 63, w = t >> 6;
  int wm = (w & 1) * 32, wn = (w >> 1) * 32;
  int q = lane >> 4, mr = lane & 15;
  for (int c0 = 0; c0 < K; c0 += 64) {
    if (c0) __syncthreads();
#pragma unroll
    for (int rep = 0; rep < 2; rep++) {
      int s = t + rep * 256;
      int row = s >> 3, kseg = (s & 7) * 8;
      long aoff = (arow0 + row) * (long)K + c0 + kseg;
      int doff = row * KP + kseg;
      *(uint4*)(sAh + doff) = *(const uint4*)(Ah + aoff);
      *(uint4*)(sAl + doff) = *(const uint4*)(Al + aoff);
      if (NMAX >= 64 || (nbase + row) < NMAX) {
        long boff = (long)(nbase + row) * K + c0 + kseg;
        *(uint4*)(sBh + doff) = *(const uint4*)(Bh + boff);
        *(uint4*)(sBl + doff) = *(const uint4*)(Bl + boff);
      } else {
        uint4 z = make_uint4(0u, 0u, 0u, 0u);
        *(uint4*)(sBh + doff) = z;
        *(uint4*)(sBl + doff) = z;
      }
    }
    __syncthreads();
#pragma unroll
    for (int k0 = 0; k0 < 64; k0 += 32) {
      s8v ah[2], al[2], bh[2], bl[2];
#pragma unroll
      for (int mt = 0; mt < 2; mt++) {
        int off = (wm + mt * 16 + mr) * KP + k0 + q * 8;
        ah[mt] = *(const s8v*)(sAh + off);
        al[mt] = *(const s8v*)(sAl + off);
      }
#pragma unroll
      for (int nt = 0; nt < 2; nt++) {
        int off = (wn + nt * 16 + mr) * KP + k0 + q * 8;
        bh[nt] = *(const s8v*)(sBh + off);
        bl[nt] = *(const s8v*)(sBl + off);
      }
#pragma unroll
      for (int mt = 0; mt < 2; mt++)
#pragma unroll
        for (int nt = 0; nt < 2; nt++) {
          acc[mt][nt] = __builtin_amdgcn_mfma_f32_16x16x32_bf16(ah[mt], bh[nt], acc[mt][nt], 0, 0, 0);
          acc[mt][nt] = __builtin_amdgcn_mfma_f32_16x16x32_bf16(ah[mt], bl[nt], acc[mt][nt], 0, 0, 0);
          acc[mt][nt] = __builtin_amdgcn_mfma_f32_16x16x32_bf16(al[mt], bh[nt], acc[mt][nt], 0, 0, 0);
        }
    }
  }
}

// ---------------- weight split ----------------
__global__ void k_wsplit4(const float* __restrict__ gw, const float* __restrict__ ipw,
                          const float* __restrict__ xw, const float* __restrict__ opw,
                          ushort_t* __restrict__ base) {
  int i = blockIdx.x * 256 + threadIdx.x;
  const float* src; ushort_t *dh, *dl; int off;
  if (i < 36864)        { src = gw;  off = i;           dh = base;          dl = base + 36864; }
  else if (i < 184320)  { src = ipw; off = i - 36864;   dh = base + 73728;  dl = base + 221184; }
  else if (i < 201216)  { src = xw;  off = i - 184320;  dh = base + 368640; dl = base + 385536; }
  else if (i < 274944)  { src = opw; off = i - 201216;  dh = base + 402432; dl = base + 476160; }
  else return;
  float v = src[off];
  unsigned int h = f2bf(v);
  dh[off] = (ushort_t)h;
  dl[off] = (ushort_t)f2bf(v - bf2f(h));
}

// ---------------- pre: transpose x,guide (b,c,l)->(b,l,c); guide also split ----------------
__global__ void k_pre(const float* __restrict__ x, const float* __restrict__ guide,
                      float* __restrict__ xT, ushort_t* __restrict__ gTh,
                      ushort_t* __restrict__ gTl) {
  __shared__ float sx[64 * 68];
  __shared__ float sg[64 * 68];
  int t = threadIdx.x;
  int l0 = blockIdx.x * 64;
  int c0 = blockIdx.y * 64;
  int b  = blockIdx.z;
#pragma unroll
  for (int ii = 0; ii < 4; ii++) {
    int ci = (t >> 4) + ii * 16;
    int j4 = (t & 15) * 4;
    long src = ((long)(b * 192 + c0 + ci)) * Lseq + l0 + j4;
    *(float4*)(sx + ci * 68 + j4) = *(const float4*)(x + src);
    *(float4*)(sg + ci * 68 + j4) = *(const float4*)(guide + src);
  }
  __syncthreads();
#pragma unroll
  for (int ii = 0; ii < 4; ii++) {
    int li = (t >> 4) + ii * 16;
    int c4 = (t & 15) * 4;
    long dst = ((long)(b * Lseq + l0 + li)) * 192 + c0 + c4;
    float4 xv = make_float4(sx[(c4 + 0) * 68 + li], sx[(c4 + 1) * 68 + li],
                            sx[(c4 + 2) * 68 + li], sx[(c4 + 3) * 68 + li]);
    *(float4*)(xT + dst) = xv;
    float gv[4];
#pragma unroll
    for (int j = 0; j < 4; j++) gv[j] = sg[(c4 + j) * 68 + li];
    ushort4 hv, lv;
    unsigned int h0 = f2bf(gv[0]), h1 = f2bf(gv[1]), h2 = f2bf(gv[2]), h3 = f2bf(gv[3]);
    hv.x = h0; hv.y = h1; hv.z = h2; hv.w = h3;
    lv.x = (ushort_t)f2bf(gv[0] - bf2f(h0));
    lv.y = (ushort_t)f2bf(gv[1] - bf2f(h1));
    lv.z = (ushort_t)f2bf(gv[2] - bf2f(h2));
    lv.w = (ushort_t)f2bf(gv[3] - bf2f(h3));
    *(ushort4*)(gTh + dst) = hv;
    *(ushort4*)(gTl + dst) = lv;
  }
}

// ---------------- guide GEMM (MFMA) ----------------
__global__ __launch_bounds__(256) void k_guide_mfma(
    const ushort_t* __restrict__ Ah, const ushort_t* __restrict__ Al,
    const ushort_t* __restrict__ Bh, const ushort_t* __restrict__ Bl,
    const float* __restrict__ xT, float* __restrict__ gxT) {
  __shared__ __align__(16) ushort_t smem[4 * 64 * KP];
  ushort_t* sAh = smem;
  ushort_t* sAl = smem + 64 * KP;
  ushort_t* sBh = smem + 2 * 64 * KP;
  ushort_t* sBl = smem + 3 * 64 * KP;
  int t = threadIdx.x;
  int rowbase = blockIdx.x * 64;
  int nbase = blockIdx.y * 64;
  int lane = t & 63, w = t >> 6;
  int wm = (w & 1) * 32, wn = (w >> 1) * 32;
  int q = lane >> 4, mr = lane & 15;
  f4v acc[2][2];
#pragma unroll
  for (int i = 0; i < 2; i++)
#pragma unroll
    for (int j = 0; j < 2; j++) acc[i][j] = (f4v){0.f, 0.f, 0.f, 0.f};
  mfma_gemm64<192, 192>(Ah, Al, rowbase, Bh, Bl, nbase, sAh, sAl, sBh, sBl, acc);
#pragma unroll
  for (int mt = 0; mt < 2; mt++)
#pragma unroll
    for (int nt = 0; nt < 2; nt++) {
      int row = rowbase + wm + mt * 16 + q * 4;
      int col = nbase + wn + nt * 16 + mr;
#pragma unroll
      for (int r = 0; r < 4; r++) {
        long idx = (long)(row + r) * 192 + col;
        gxT[idx] = acc[mt][nt][r] + xT[idx];
      }
    }
}

// ---------------- row-major LayerNorm ----------------
__global__ void k_lnT(const float* __restrict__ gxT, const float* __restrict__ ln_g,
                      const float* __restrict__ ln_b, ushort_t* __restrict__ seqh,
                      ushort_t* __restrict__ seql) {
  int t = threadIdx.x;
  int r = blockIdx.x * 4 + (t >> 6);
  int lane = t & 63;
  const float* p = gxT + (long)r * 192;
  float v0 = p[lane], v1 = p[lane + 64], v2 = p[lane + 128];
  float sum = v0 + v1 + v2;
  float sq = fmaf(v0, v0, fmaf(v1, v1, v2 * v2));
#pragma unroll
  for (int off = 1; off < 64; off <<= 1) {
    sum += __shfl_xor(sum, off);
    sq  += __shfl_xor(sq, off);
  }
  float mu = sum / 192.f;
  float rstd = rsqrtf(sq / 192.f - mu * mu + 1e-5f);
  long base = (long)r * 192;
#pragma unroll
  for (int j = 0; j < 3; j++) {
    int c = lane + j * 64;
    float v = (p[c] - mu) * rstd * ln_g[c] + ln_b[c];
    unsigned int h = f2bf(v);
    seqh[base + c] = (ushort_t)h;
    seql[base + c] = (ushort_t)f2bf(v - bf2f(h));
  }
}

// ---------------- in_proj (MFMA) ----------------
__global__ __launch_bounds__(256) void k_inproj_mfma(
    const ushort_t* __restrict__ Ah, const ushort_t* __restrict__ Al,
    const ushort_t* __restrict__ Bh, const ushort_t* __restrict__ Bl,
    float* __restrict__ xzu, float* __restrict__ z) {
  __shared__ __align__(16) ushort_t smem[4 * 64 * KP];
  ushort_t* sAh = smem;
  ushort_t* sAl = smem + 64 * KP;
  ushort_t* sBh = smem + 2 * 64 * KP;
  ushort_t* sBl = smem + 3 * 64 * KP;
  int t = threadIdx.x;
  int rowbase = blockIdx.x * 64;
  int nbase = blockIdx.y * 64;
  int lane = t & 63, w = t >> 6;
  int wm = (w & 1) * 32, wn = (w >> 1) * 32;
  int q = lane >> 4, mr = lane & 15;
  f4v acc[2][2];
#pragma unroll
  for (int i = 0; i < 2; i++)
#pragma unroll
    for (int j = 0; j < 2; j++) acc[i][j] = (f4v){0.f, 0.f, 0.f, 0.f};
  mfma_gemm64<192, 768>(Ah, Al, rowbase, Bh, Bl, nbase, sAh, sAl, sBh, sBl, acc);
  float* dst = (nbase < 384) ? xzu : z;
  int cb = (nbase < 384) ? nbase : nbase - 384;
#pragma unroll
  for (int mt = 0; mt < 2; mt++)
#pragma unroll
    for (int nt = 0; nt < 2; nt++) {
      int row = rowbase + wm + mt * 16 + q * 4;
      int col = cb + wn + nt * 16 + mr;
#pragma unroll
      for (int r = 0; r < 4; r++)
        dst[(long)(row + r) * 384 + col] = acc[mt][nt][r];
    }
}

// ---------------- conv4 + SiLU -> u bf16 hi/lo only (for xproj) ----------------
__global__ void k_conv(const float* __restrict__ xzu, const float* __restrict__ cw,
                       const float* __restrict__ cb, ushort_t* __restrict__ uh,
                       ushort_t* __restrict__ ul) {
  int idx = blockIdx.x * 256 + threadIdx.x;
  if (idx >= Bsz * Lseq * Din) return;
  int d = idx % Din;
  int l = (idx / Din) % Lseq;
  float acc = cb[d];
#pragma unroll
  for (int k = 0; k < 4; k++) {
    int ls = l - 3 + k;
    if (ls >= 0) acc = fmaf(xzu[idx - (3 - k) * 384], cw[d * 4 + k], acc);
  }
  float v = acc / (1.f + __expf(-acc));
  unsigned int h = f2bf(v);
  uh[idx] = (ushort_t)h;
  ul[idx] = (ushort_t)f2bf(v - bf2f(h));
}

// ---------------- x_proj (MFMA): dbc[row, r<44] pitch 48 ----------------
__global__ __launch_bounds__(256) void k_xproj_mfma(
    const ushort_t* __restrict__ Ah, const ushort_t* __restrict__ Al,
    const ushort_t* __restrict__ Bh, const ushort_t* __restrict__ Bl,
    float* __restrict__ dbc) {
  __shared__ __align__(16) ushort_t smem[4 * 64 * KP];
  ushort_t* sAh = smem;
  ushort_t* sAl = smem + 64 * KP;
  ushort_t* sBh = smem + 2 * 64 * KP;
  ushort_t* sBl = smem + 3 * 64 * KP;
  int t = threadIdx.x;
  int rowbase = blockIdx.x * 64;
  int lane = t & 63, w = t >> 6;
  int wm = (w & 1) * 32, wn = (w >> 1) * 32;
  int q = lane >> 4, mr = lane & 15;
  f4v acc[2][2];
#pragma unroll
  for (int i = 0; i < 2; i++)
#pragma unroll
    for (int j = 0; j < 2; j++) acc[i][j] = (f4v){0.f, 0.f, 0.f, 0.f};
  mfma_gemm64<384, 44>(Ah, Al, rowbase, Bh, Bl, 0, sAh, sAl, sBh, sBl, acc);
#pragma unroll
  for (int mt = 0; mt < 2; mt++)
#pragma unroll
    for (int nt = 0; nt < 2; nt++) {
      int row = rowbase + wm + mt * 16 + q * 4;
      int col = wn + nt * 16 + mr;
      if (col < 44) {
#pragma unroll
        for (int r = 0; r < 4; r++)
          dbc[(long)(row + r) * 48 + col] = acc[mt][nt][r];
      }
    }
}

// ---------------- prep: A = -exp(A_log), rA = 1/A ----------------
__global__ void k_prep(const float* __restrict__ Alog, float* __restrict__ Aexp,
                       float* __restrict__ rAe) {
  int i = blockIdx.x * 256 + threadIdx.x;
  if (i < Din * Dst) {
    float A = -__expf(Alog[i]);
    Aexp[i] = A;
    rAe[i] = 1.f / A;
  }
}

// ======================= fused scans =======================
// Thread layout: t = 2*dl + half; d = dg*192+dl owns n in [half*8, half*8+8).
// Recomputes u (rolling conv window from xzu) and dt (from dbc, shfl-split
// 12-tap dot) in-register; reads B/C straight from dbc (pitch 48).
__device__ __forceinline__ float softplus_f(float x) {
  return (x > 20.f) ? x : __logf(1.f + __expf(x));
}

__global__ __launch_bounds__(384) void k_scanA(
    const float* __restrict__ xzu, const float* __restrict__ dbc,
    const float* __restrict__ cw, const float* __restrict__ cb,
    const float* __restrict__ dtw, const float* __restrict__ dtb,
    const float* __restrict__ Aexp, const float* __restrict__ rAe,
    float* __restrict__ Ssum, float* __restrict__ Sdt) {
  int t = threadIdx.x;
  int dl = t >> 1, half = t & 1;
  int dg = blockIdx.y;
  int d = dg * 192 + dl;
  int c = blockIdx.x, b = blockIdx.z;
  float A[8], rA[8];
  {
    float4 a0 = *(const float4*)(Aexp + d * 16 + half * 8);
    float4 a1 = *(const float4*)(Aexp + d * 16 + half * 8 + 4);
    float4 r0 = *(const float4*)(rAe + d * 16 + half * 8);
    float4 r1 = *(const float4*)(rAe + d * 16 + half * 8 + 4);
    A[0]=a0.x;A[1]=a0.y;A[2]=a0.z;A[3]=a0.w;A[4]=a1.x;A[5]=a1.y;A[6]=a1.z;A[7]=a1.w;
    rA[0]=r0.x;rA[1]=r0.y;rA[2]=r0.z;rA[3]=r0.w;rA[4]=r1.x;rA[5]=r1.y;rA[6]=r1.z;rA[7]=r1.w;
  }
  float cwd[4];
#pragma unroll
  for (int k = 0; k < 4; k++) cwd[k] = cw[d * 4 + k];
  float cbd = cb[d];
  float wt[6];
#pragma unroll
  for (int r = 0; r < 4; r++) wt[r] = dtw[d * 12 + half * 8 + r];
  wt[4] = dtw[d * 12 + 4 + half * 2];
  wt[5] = dtw[d * 12 + 4 + half * 2 + 1];
  float dtbd = dtb[d];
  long row0 = (long)b * Lseq + (long)c * CLk;
  float w1 = 0.f, w2 = 0.f, w3 = 0.f;
  if (c > 0) {
    w3 = xzu[(row0 - 3) * 384 + d];
    w2 = xzu[(row0 - 2) * 384 + d];
    w1 = xzu[(row0 - 1) * 384 + d];
  }
  float h[8];
#pragma unroll
  for (int n = 0; n < 8; n++) h[n] = 0.f;
  float sdt = 0.f;
  const float* xp = xzu + row0 * 384 + d;
  const float* dp = dbc + row0 * 48;
#pragma unroll 2
  for (int i = 0; i < CLk; i++) {
    float x0 = xp[i * 384];
    float ua = cbd;
    ua = fmaf(w3, cwd[0], ua); ua = fmaf(w2, cwd[1], ua);
    ua = fmaf(w1, cwd[2], ua); ua = fmaf(x0, cwd[3], ua);
    float uv = ua / (1.f + __expf(-ua));
    w3 = w2; w2 = w1; w1 = x0;
    float4 qa = *(const float4*)(dp + i * 48 + half * 8);
    float2 qb = *(const float2*)(dp + i * 48 + 4 + half * 2);
    float part = qa.x * wt[0] + qa.y * wt[1] + qa.z * wt[2] + qa.w * wt[3]
               + qb.x * wt[4] + qb.y * wt[5];
    float dtv = softplus_f(part + __shfl_xor(part, 1) + dtbd);
    sdt += dtv;
    float4 b0 = *(const float4*)(dp + i * 48 + 12 + half * 8);
    float4 b1 = *(const float4*)(dp + i * 48 + 16 + half * 8);
    float Bv[8] = {b0.x, b0.y, b0.z, b0.w, b1.x, b1.y, b1.z, b1.w};
#pragma unroll
    for (int n = 0; n < 8; n++) {
      float a = __expf(dtv * A[n]);
      float q = rA[n] * Bv[n] * uv;
      h[n] = fmaf(a, h[n] + q, -q);
    }
  }
  long o = ((long)(b * NCk + c) * 384 + d);
  if (half == 0) Sdt[o] = sdt;
  *(float4*)(Ssum + o * 16 + half * 8)     = make_float4(h[0], h[1], h[2], h[3]);
  *(float4*)(Ssum + o * 16 + half * 8 + 4) = make_float4(h[4], h[5], h[6], h[7]);
}

// ---------------- scanB (unchanged logic) ----------------
__global__ void k_scanB(const float* __restrict__ Ssum, const float* __restrict__ Sdt,
                        const float* __restrict__ Aexp, float* __restrict__ Hst) {
  int g = blockIdx.x * 256 + threadIdx.x;
  int n = g & 15;
  int d = (g >> 4) % 384;
  int b = g / (384 * 16);
  float A = Aexp[d * 16 + n];
  float h = 0.f;
  for (int c = 0; c < NCk; c++) {
    long o = ((long)(b * NCk + c) * 384 + d);
    float aC = __expf(A * Sdt[o]);
    Hst[o * 16 + n] = h;
    h = fmaf(aC, h, Ssum[o * 16 + n]);
  }
}

// ---------------- scanC: replay + y + gate, fused conv/dt, emit y bf16 hi/lo ----------------
__global__ __launch_bounds__(384) void k_scanC(
    const float* __restrict__ xzu, const float* __restrict__ dbc,
    const float* __restrict__ cw, const float* __restrict__ cb,
    const float* __restrict__ dtw, const float* __restrict__ dtb,
    const float* __restrict__ Aexp, const float* __restrict__ rAe,
    const float* __restrict__ Hst, const float* __restrict__ Dp,
    const float* __restrict__ z, ushort_t* __restrict__ yyh,
    ushort_t* __restrict__ yyl) {
  int t = threadIdx.x;
  int dl = t >> 1, half = t & 1;
  int dg = blockIdx.y;
  int d = dg * 192 + dl;
  int c = blockIdx.x, b = blockIdx.z;
  float A[8], rA[8];
  {
    float4 a0 = *(const float4*)(Aexp + d * 16 + half * 8);
    float4 a1 = *(const float4*)(Aexp + d * 16 + half * 8 + 4);
    float4 r0 = *(const float4*)(rAe + d * 16 + half * 8);
    float4 r1 = *(const float4*)(rAe + d * 16 + half * 8 + 4);
    A[0]=a0.x;A[1]=a0.y;A[2]=a0.z;A[3]=a0.w;A[4]=a1.x;A[5]=a1.y;A[6]=a1.z;A[7]=a1.w;
    rA[0]=r0.x;rA[1]=r0.y;rA[2]=r0.z;rA[3]=r0.w;rA[4]=r1.x;rA[5]=r1.y;rA[6]=r1.z;rA[7]=r1.w;
  }
  float cwd[4];
#pragma unroll
  for (int k = 0; k < 4; k++) cwd[k] = cw[d * 4 + k];
  float cbd = cb[d];
  float wt[6];
#pragma unroll
  for (int r = 0; r < 4; r++) wt[r] = dtw[d * 12 + half * 8 + r];
  wt[4] = dtw[d * 12 + 4 + half * 2];
  wt[5] = dtw[d * 12 + 4 + half * 2 + 1];
  float dtbd = dtb[d];
  float Dv = Dp[d];
  long o = ((long)(b * NCk + c) * 384 + d);
  float h[8];
  {
    float4 h0 = *(const float4*)(Hst + o * 16 + half * 8);
    float4 h1 = *(const float4*)(Hst + o * 16 + half * 8 + 4);
    h[0]=h0.x;h[1]=h0.y;h[2]=h0.z;h[3]=h0.w;h[4]=h1.x;h[5]=h1.y;h[6]=h1.z;h[7]=h1.w;
  }
  long row0 = (long)b * Lseq + (long)c * CLk;
  float w1 = 0.f, w2 = 0.f, w3 = 0.f;
  if (c > 0) {
    w3 = xzu[(row0 - 3) * 384 + d];
    w2 = xzu[(row0 - 2) * 384 + d];
    w1 = xzu[(row0 - 1) * 384 + d];
  }
  const float* xp = xzu + row0 * 384 + d;
  const float* dp = dbc + row0 * 48;
  const float* zp = z + row0 * 384 + d;
#pragma unroll 2
  for (int i = 0; i < CLk; i++) {
    float x0 = xp[i * 384];
    float ua = cbd;
    ua = fmaf(w3, cwd[0], ua); ua = fmaf(w2, cwd[1], ua);
    ua = fmaf(w1, cwd[2], ua); ua = fmaf(x0, cwd[3], ua);
    float uv = ua / (1.f + __expf(-ua));
    w3 = w2; w2 = w1; w1 = x0;
    float4 qa = *(const float4*)(dp + i * 48 + half * 8);
    float2 qb = *(const float2*)(dp + i * 48 + 4 + half * 2);
    float part = qa.x * wt[0] + qa.y * wt[1] + qa.z * wt[2] + qa.w * wt[3]
               + qb.x * wt[4] + qb.y * wt[5];
    float dtv = softplus_f(part + __shfl_xor(part, 1) + dtbd);
    float4 b0 = *(const float4*)(dp + i * 48 + 12 + half * 8);
    float4 b1 = *(const float4*)(dp + i * 48 + 16 + half * 8);
    float Bv[8] = {b0.x, b0.y, b0.z, b0.w, b1.x, b1.y, b1.z, b1.w};
    float4 c0v = *(const float4*)(dp + i * 48 + 28 + half * 8);
    float4 c1v = *(const float4*)(dp + i * 48 + 32 + half * 8);
    float Cv[8] = {c0v.x, c0v.y, c0v.z, c0v.w, c1v.x, c1v.y, c1v.z, c1v.w};
    float yacc = 0.f;
#pragma unroll
    for (int n = 0; n < 8; n++) {
      float a = __expf(dtv * A[n]);
      float q = rA[n] * Bv[n] * uv;
      h[n] = fmaf(a, h[n] + q, -q);
      yacc = fmaf(h[n], Cv[n], yacc);
    }
    float ytot = yacc + __shfl_xor(yacc, 1);
    if (half == 0) {
      float zv = zp[i * 384];
      float sil = zv / (1.f + __expf(-zv));
      float yv = (ytot + uv * Dv) * sil;
      unsigned int hb = f2bf(yv);
      yyh[row0 * 384 + i * 384 + d] = (ushort_t)hb;
      yyl[row0 * 384 + i * 384 + d] = (ushort_t)f2bf(yv - bf2f(hb));
    }
  }
}

// ---------------- out_proj (MFMA) with LDS transpose epilogue ----------------
__global__ __launch_bounds__(256) void k_outproj_mfma(
    const ushort_t* __restrict__ Ah, const ushort_t* __restrict__ Al,
    const ushort_t* __restrict__ Bh, const ushort_t* __restrict__ Bl,
    float* __restrict__ out) {
  __shared__ __align__(16) ushort_t smem[4 * 64 * KP];
  ushort_t* sAh = smem;
  ushort_t* sAl = smem + 64 * KP;
  ushort_t* sBh = smem + 2 * 64 * KP;
  ushort_t* sBl = smem + 3 * 64 * KP;
  float* sC = (float*)smem;
  int t = threadIdx.x;
  int rowbase = blockIdx.x * 64;
  int nbase = blockIdx.y * 64;
  int lane = t & 63, w = t >> 6;
  int wm = (w & 1) * 32, wn = (w >> 1) * 32;
  int q = lane >> 4, mr = lane & 15;
  f4v acc[2][2];
#pragma unroll
  for (int i = 0; i < 2; i++)
#pragma unroll
    for (int j = 0; j < 2; j++) acc[i][j] = (f4v){0.f, 0.f, 0.f, 0.f};
  mfma_gemm64<384, 192>(Ah, Al, rowbase, Bh, Bl, nbase, sAh, sAl, sBh, sBl, acc);
  __syncthreads();
#pragma unroll
  for (int mt = 0; mt < 2; mt++)
#pragma unroll
    for (int nt = 0; nt < 2; nt++) {
      int rloc = wm + mt * 16 + q * 4;
      int cloc = wn + nt * 16 + mr;
#pragma unroll
      for (int r = 0; r < 4; r++)
        sC[(rloc + r) * 68 + cloc] = acc[mt][nt][r];
    }
  __syncthreads();
  int b = rowbase >> 12;
  int l0 = rowbase & 4095;
  int o = t >> 2;
  int lg = (t & 3) * 16;
  long obase = ((long)(b * 192 + nbase + o)) * Lseq + l0 + lg;
#pragma unroll
  for (int j4 = 0; j4 < 4; j4++) {
    float4 v = make_float4(sC[(lg + j4 * 4 + 0) * 68 + o], sC[(lg + j4 * 4 + 1) * 68 + o],
                           sC[(lg + j4 * 4 + 2) * 68 + o], sC[(lg + j4 * 4 + 3) * 68 + o]);
    *(float4*)(out + obase + j4 * 4) = v;
  }
}

extern "C" void kernel_launch(void* const* d_in, const int* in_sizes, int n_in,
                              void* d_out, int out_size, void* d_ws, size_t ws_size,
                              hipStream_t stream) {
  const float* x    = (const float*)d_in[0];
  const float* guide= (const float*)d_in[1];
  const float* gw   = (const float*)d_in[2];
  const float* ln_g = (const float*)d_in[3];
  const float* ln_b = (const float*)d_in[4];
  const float* ipw  = (const float*)d_in[5];
  const float* cw   = (const float*)d_in[6];
  const float* cb   = (const float*)d_in[7];
  const float* xpw  = (const float*)d_in[8];
  const float* dtw  = (const float*)d_in[9];
  const float* dtb  = (const float*)d_in[10];
  const float* Alog = (const float*)d_in[11];
  const float* Dp   = (const float*)d_in[12];
  const float* opw  = (const float*)d_in[13];
  float* out = (float*)d_out;
  float* ws  = (float*)d_ws;

  // Workspace (float offsets), lifetime-packed, max 32465408 < proven 34340864:
  // R0 [0,3145728):        xT[pre->guide] | uh(us)[conv->xproj] | Ssum[scanA->scanB] | yyh(us)[scanC->outproj]
  // R1 [3145728,6291456):  gTh+gTl(us)[pre->guide] | ul(us)[conv->xproj] | Hst[scanB->scanC]
  // R2 [6291456,9437184):  gxT[guide->lnT] | dbc[xproj->scanC] (786432 f)
  // R3 [9437184,12582912): seqh+seql(us)[lnT->inproj] | yyl(us)[scanC->outproj]
  // R4 [12582912,18874368): z [inproj->scanC]
  // R5 [18874368,25165824): xzu [inproj->scanC]
  float* xT   = ws + 0;
  ushort_t* uh   = (ushort_t*)(ws + 0);
  float* Ssum = ws + 0;
  ushort_t* yyh  = (ushort_t*)(ws + 0);
  ushort_t* gTh  = (ushort_t*)(ws + 3145728);
  ushort_t* gTl  = (ushort_t*)(ws + 3145728 + 1572864);
  ushort_t* ul   = (ushort_t*)(ws + 3145728);
  float* Hst  = ws + 3145728;
  float* gxT  = ws + 6291456;
  float* dbc  = ws + 6291456;
  ushort_t* seqh = (ushort_t*)(ws + 9437184);
  ushort_t* seql = (ushort_t*)(ws + 9437184 + 1572864);
  ushort_t* yyl  = (ushort_t*)(ws + 9437184);
  float* z    = ws + 12582912;
  float* xzu  = ws + 18874368;
  float* Sdt  = ws + 31981568;  // 196608
  float* Aexp = ws + 32178176;  // 6144
  float* rAe  = ws + 32184320;  // 6144
  ushort_t* wsplit = (ushort_t*)(ws + 32190464);   // 549888 ushorts
  ushort_t* gwh = wsplit;
  ushort_t* gwl = wsplit + 36864;
  ushort_t* iwh = wsplit + 73728;
  ushort_t* iwl = wsplit + 221184;
  ushort_t* xwh = wsplit + 368640;
  ushort_t* xwl = wsplit + 385536;
  ushort_t* opwh = wsplit + 402432;
  ushort_t* opwl = wsplit + 476160;

  k_prep    <<<24,               256, 0, stream>>>(Alog, Aexp, rAe);
  k_wsplit4 <<<1074,             256, 0, stream>>>(gw, ipw, xpw, opw, wsplit);
  k_pre     <<<dim3(64, 3, 4),   256, 0, stream>>>(x, guide, xT, gTh, gTl);
  k_guide_mfma<<<dim3(256, 3),   256, 0, stream>>>(gTh, gTl, gwh, gwl, xT, gxT);
  k_lnT     <<<4096,             256, 0, stream>>>(gxT, ln_g, ln_b, seqh, seql);
  k_inproj_mfma<<<dim3(256, 12), 256, 0, stream>>>(seqh, seql, iwh, iwl, xzu, z);
  k_conv    <<<24576,            256, 0, stream>>>(xzu, cw, cb, uh, ul);
  k_xproj_mfma<<<256,            256, 0, stream>>>(uh, ul, xwh, xwl, dbc);
  k_scanA   <<<dim3(NCk, 2, Bsz), 384, 0, stream>>>(xzu, dbc, cw, cb, dtw, dtb, Aexp, rAe, Ssum, Sdt);
  k_scanB   <<<96,               256, 0, stream>>>(Ssum, Sdt, Aexp, Hst);
  k_scanC   <<<dim3(NCk, 2, Bsz), 384, 0, stream>>>(xzu, dbc, cw, cb, dtw, dtb, Aexp, rAe, Hst, Dp, z, yyh, yyl);
  k_outproj_mfma<<<dim3(256, 3), 256, 0, stream>>>(yyh, yyl, opwh, opwl, out);
}

// Round 8
// 323.927 us; speedup vs baseline: 1.0564x; 1.0564x over previous
//
#include <hip/hip_runtime.h>
#include <hip/hip_bf16.h>

#define Bsz 4
#define Cm 192
#define Lseq 4096
#define Din 384
#define Dst 16
#define NCk 256
#define CLk 16    // Lseq/NCk

typedef short s8v __attribute__((ext_vector_type(8)));
typedef float f4v __attribute__((ext_vector_type(4)));
typedef unsigned short ushort_t;

__device__ __forceinline__ unsigned int f2bf(float v) {
  unsigned int u = __float_as_uint(v);
  return (u + 0x7FFFu + ((u >> 16) & 1u)) >> 16;
}
__device__ __forceinline__ float bf2f(unsigned int h) {
  return __uint_as_float(h << 16);
}

// ======================= split-bf16 MFMA GEMM core =======================
#define KP 72

template<int K, int NMAX>
__device__ __forceinline__ void mfma_gemm64(
    const ushort_t* __restrict__ Ah, const ushort_t* __restrict__ Al, long arow0,
    const ushort_t* __restrict__ Bh, const ushort_t* __restrict__ Bl, int nbase,
    ushort_t* sAh, ushort_t* sAl, ushort_t* sBh, ushort_t* sBl,
    f4v acc[2][2]) {
  int t = threadIdx.x;
  int lane = t & 63, w = t >> 6;
  int wm = (w & 1) * 32, wn = (w >> 1) * 32;
  int q = lane >> 4, mr = lane & 15;
  for (int c0 = 0; c0 < K; c0 += 64) {
    if (c0) __syncthreads();
#pragma unroll
    for (int rep = 0; rep < 2; rep++) {
      int s = t + rep * 256;
      int row = s >> 3, kseg = (s & 7) * 8;
      long aoff = (arow0 + row) * (long)K + c0 + kseg;
      int doff = row * KP + kseg;
      *(uint4*)(sAh + doff) = *(const uint4*)(Ah + aoff);
      *(uint4*)(sAl + doff) = *(const uint4*)(Al + aoff);
      if (NMAX >= 64 || (nbase + row) < NMAX) {
        long boff = (long)(nbase + row) * K + c0 + kseg;
        *(uint4*)(sBh + doff) = *(const uint4*)(Bh + boff);
        *(uint4*)(sBl + doff) = *(const uint4*)(Bl + boff);
      } else {
        uint4 z = make_uint4(0u, 0u, 0u, 0u);
        *(uint4*)(sBh + doff) = z;
        *(uint4*)(sBl + doff) = z;
      }
    }
    __syncthreads();
#pragma unroll
    for (int k0 = 0; k0 < 64; k0 += 32) {
      s8v ah[2], al[2], bh[2], bl[2];
#pragma unroll
      for (int mt = 0; mt < 2; mt++) {
        int off = (wm + mt * 16 + mr) * KP + k0 + q * 8;
        ah[mt] = *(const s8v*)(sAh + off);
        al[mt] = *(const s8v*)(sAl + off);
      }
#pragma unroll
      for (int nt = 0; nt < 2; nt++) {
        int off = (wn + nt * 16 + mr) * KP + k0 + q * 8;
        bh[nt] = *(const s8v*)(sBh + off);
        bl[nt] = *(const s8v*)(sBl + off);
      }
#pragma unroll
      for (int mt = 0; mt < 2; mt++)
#pragma unroll
        for (int nt = 0; nt < 2; nt++) {
          acc[mt][nt] = __builtin_amdgcn_mfma_f32_16x16x32_bf16(ah[mt], bh[nt], acc[mt][nt], 0, 0, 0);
          acc[mt][nt] = __builtin_amdgcn_mfma_f32_16x16x32_bf16(ah[mt], bl[nt], acc[mt][nt], 0, 0, 0);
          acc[mt][nt] = __builtin_amdgcn_mfma_f32_16x16x32_bf16(al[mt], bh[nt], acc[mt][nt], 0, 0, 0);
        }
    }
  }
}

// ---------------- weight split ----------------
__global__ void k_wsplit4(const float* __restrict__ gw, const float* __restrict__ ipw,
                          const float* __restrict__ xw, const float* __restrict__ opw,
                          ushort_t* __restrict__ base) {
  int i = blockIdx.x * 256 + threadIdx.x;
  const float* src; ushort_t *dh, *dl; int off;
  if (i < 36864)        { src = gw;  off = i;           dh = base;          dl = base + 36864; }
  else if (i < 184320)  { src = ipw; off = i - 36864;   dh = base + 73728;  dl = base + 221184; }
  else if (i < 201216)  { src = xw;  off = i - 184320;  dh = base + 368640; dl = base + 385536; }
  else if (i < 274944)  { src = opw; off = i - 201216;  dh = base + 402432; dl = base + 476160; }
  else return;
  float v = src[off];
  unsigned int h = f2bf(v);
  dh[off] = (ushort_t)h;
  dl[off] = (ushort_t)f2bf(v - bf2f(h));
}

// ---------------- pre: transpose x,guide (b,c,l)->(b,l,c); guide also split ----------------
__global__ void k_pre(const float* __restrict__ x, const float* __restrict__ guide,
                      float* __restrict__ xT, ushort_t* __restrict__ gTh,
                      ushort_t* __restrict__ gTl) {
  __shared__ float sx[64 * 68];
  __shared__ float sg[64 * 68];
  int t = threadIdx.x;
  int l0 = blockIdx.x * 64;
  int c0 = blockIdx.y * 64;
  int b  = blockIdx.z;
#pragma unroll
  for (int ii = 0; ii < 4; ii++) {
    int ci = (t >> 4) + ii * 16;
    int j4 = (t & 15) * 4;
    long src = ((long)(b * 192 + c0 + ci)) * Lseq + l0 + j4;
    *(float4*)(sx + ci * 68 + j4) = *(const float4*)(x + src);
    *(float4*)(sg + ci * 68 + j4) = *(const float4*)(guide + src);
  }
  __syncthreads();
#pragma unroll
  for (int ii = 0; ii < 4; ii++) {
    int li = (t >> 4) + ii * 16;
    int c4 = (t & 15) * 4;
    long dst = ((long)(b * Lseq + l0 + li)) * 192 + c0 + c4;
    float4 xv = make_float4(sx[(c4 + 0) * 68 + li], sx[(c4 + 1) * 68 + li],
                            sx[(c4 + 2) * 68 + li], sx[(c4 + 3) * 68 + li]);
    *(float4*)(xT + dst) = xv;
    float gv[4];
#pragma unroll
    for (int j = 0; j < 4; j++) gv[j] = sg[(c4 + j) * 68 + li];
    ushort4 hv, lv;
    unsigned int h0 = f2bf(gv[0]), h1 = f2bf(gv[1]), h2 = f2bf(gv[2]), h3 = f2bf(gv[3]);
    hv.x = h0; hv.y = h1; hv.z = h2; hv.w = h3;
    lv.x = (ushort_t)f2bf(gv[0] - bf2f(h0));
    lv.y = (ushort_t)f2bf(gv[1] - bf2f(h1));
    lv.z = (ushort_t)f2bf(gv[2] - bf2f(h2));
    lv.w = (ushort_t)f2bf(gv[3] - bf2f(h3));
    *(ushort4*)(gTh + dst) = hv;
    *(ushort4*)(gTl + dst) = lv;
  }
}

// ---------------- guide GEMM (MFMA) ----------------
__global__ __launch_bounds__(256) void k_guide_mfma(
    const ushort_t* __restrict__ Ah, const ushort_t* __restrict__ Al,
    const ushort_t* __restrict__ Bh, const ushort_t* __restrict__ Bl,
    const float* __restrict__ xT, float* __restrict__ gxT) {
  __shared__ __align__(16) ushort_t smem[4 * 64 * KP];
  ushort_t* sAh = smem;
  ushort_t* sAl = smem + 64 * KP;
  ushort_t* sBh = smem + 2 * 64 * KP;
  ushort_t* sBl = smem + 3 * 64 * KP;
  int t = threadIdx.x;
  int rowbase = blockIdx.x * 64;
  int nbase = blockIdx.y * 64;
  int lane = t & 63, w = t >> 6;
  int wm = (w & 1) * 32, wn = (w >> 1) * 32;
  int q = lane >> 4, mr = lane & 15;
  f4v acc[2][2];
#pragma unroll
  for (int i = 0; i < 2; i++)
#pragma unroll
    for (int j = 0; j < 2; j++) acc[i][j] = (f4v){0.f, 0.f, 0.f, 0.f};
  mfma_gemm64<192, 192>(Ah, Al, rowbase, Bh, Bl, nbase, sAh, sAl, sBh, sBl, acc);
#pragma unroll
  for (int mt = 0; mt < 2; mt++)
#pragma unroll
    for (int nt = 0; nt < 2; nt++) {
      int row = rowbase + wm + mt * 16 + q * 4;
      int col = nbase + wn + nt * 16 + mr;
#pragma unroll
      for (int r = 0; r < 4; r++) {
        long idx = (long)(row + r) * 192 + col;
        gxT[idx] = acc[mt][nt][r] + xT[idx];
      }
    }
}

// ---------------- row-major LayerNorm ----------------
__global__ void k_lnT(const float* __restrict__ gxT, const float* __restrict__ ln_g,
                      const float* __restrict__ ln_b, ushort_t* __restrict__ seqh,
                      ushort_t* __restrict__ seql) {
  int t = threadIdx.x;
  int r = blockIdx.x * 4 + (t >> 6);
  int lane = t & 63;
  const float* p = gxT + (long)r * 192;
  float v0 = p[lane], v1 = p[lane + 64], v2 = p[lane + 128];
  float sum = v0 + v1 + v2;
  float sq = fmaf(v0, v0, fmaf(v1, v1, v2 * v2));
#pragma unroll
  for (int off = 1; off < 64; off <<= 1) {
    sum += __shfl_xor(sum, off);
    sq  += __shfl_xor(sq, off);
  }
  float mu = sum / 192.f;
  float rstd = rsqrtf(sq / 192.f - mu * mu + 1e-5f);
  long base = (long)r * 192;
#pragma unroll
  for (int j = 0; j < 3; j++) {
    int c = lane + j * 64;
    float v = (p[c] - mu) * rstd * ln_g[c] + ln_b[c];
    unsigned int h = f2bf(v);
    seqh[base + c] = (ushort_t)h;
    seql[base + c] = (ushort_t)f2bf(v - bf2f(h));
  }
}

// ---------------- in_proj (MFMA) ----------------
__global__ __launch_bounds__(256) void k_inproj_mfma(
    const ushort_t* __restrict__ Ah, const ushort_t* __restrict__ Al,
    const ushort_t* __restrict__ Bh, const ushort_t* __restrict__ Bl,
    float* __restrict__ xzu, float* __restrict__ z) {
  __shared__ __align__(16) ushort_t smem[4 * 64 * KP];
  ushort_t* sAh = smem;
  ushort_t* sAl = smem + 64 * KP;
  ushort_t* sBh = smem + 2 * 64 * KP;
  ushort_t* sBl = smem + 3 * 64 * KP;
  int t = threadIdx.x;
  int rowbase = blockIdx.x * 64;
  int nbase = blockIdx.y * 64;
  int lane = t & 63, w = t >> 6;
  int wm = (w & 1) * 32, wn = (w >> 1) * 32;
  int q = lane >> 4, mr = lane & 15;
  f4v acc[2][2];
#pragma unroll
  for (int i = 0; i < 2; i++)
#pragma unroll
    for (int j = 0; j < 2; j++) acc[i][j] = (f4v){0.f, 0.f, 0.f, 0.f};
  mfma_gemm64<192, 768>(Ah, Al, rowbase, Bh, Bl, nbase, sAh, sAl, sBh, sBl, acc);
  float* dst = (nbase < 384) ? xzu : z;
  int cb = (nbase < 384) ? nbase : nbase - 384;
#pragma unroll
  for (int mt = 0; mt < 2; mt++)
#pragma unroll
    for (int nt = 0; nt < 2; nt++) {
      int row = rowbase + wm + mt * 16 + q * 4;
      int col = cb + wn + nt * 16 + mr;
#pragma unroll
      for (int r = 0; r < 4; r++)
        dst[(long)(row + r) * 384 + col] = acc[mt][nt][r];
    }
}

// ---------------- conv4 + SiLU -> u fp32 + bf16 hi/lo ----------------
__global__ void k_conv(const float* __restrict__ xzu, const float* __restrict__ cw,
                       const float* __restrict__ cb, float* __restrict__ u,
                       ushort_t* __restrict__ uh, ushort_t* __restrict__ ul) {
  int idx = blockIdx.x * 256 + threadIdx.x;
  if (idx >= Bsz * Lseq * Din) return;
  int d = idx % Din;
  int l = (idx / Din) % Lseq;
  float acc = cb[d];
#pragma unroll
  for (int k = 0; k < 4; k++) {
    int ls = l - 3 + k;
    if (ls >= 0) acc = fmaf(xzu[idx - (3 - k) * 384], cw[d * 4 + k], acc);
  }
  float v = acc / (1.f + __expf(-acc));
  u[idx] = v;
  unsigned int h = f2bf(v);
  uh[idx] = (ushort_t)h;
  ul[idx] = (ushort_t)f2bf(v - bf2f(h));
}

// ---------------- x_proj (MFMA): dbc[row, r<44] pitch 48 ----------------
__global__ __launch_bounds__(256) void k_xproj_mfma(
    const ushort_t* __restrict__ Ah, const ushort_t* __restrict__ Al,
    const ushort_t* __restrict__ Bh, const ushort_t* __restrict__ Bl,
    float* __restrict__ dbc) {
  __shared__ __align__(16) ushort_t smem[4 * 64 * KP];
  ushort_t* sAh = smem;
  ushort_t* sAl = smem + 64 * KP;
  ushort_t* sBh = smem + 2 * 64 * KP;
  ushort_t* sBl = smem + 3 * 64 * KP;
  int t = threadIdx.x;
  int rowbase = blockIdx.x * 64;
  int lane = t & 63, w = t >> 6;
  int wm = (w & 1) * 32, wn = (w >> 1) * 32;
  int q = lane >> 4, mr = lane & 15;
  f4v acc[2][2];
#pragma unroll
  for (int i = 0; i < 2; i++)
#pragma unroll
    for (int j = 0; j < 2; j++) acc[i][j] = (f4v){0.f, 0.f, 0.f, 0.f};
  mfma_gemm64<384, 44>(Ah, Al, rowbase, Bh, Bl, 0, sAh, sAl, sBh, sBl, acc);
#pragma unroll
  for (int mt = 0; mt < 2; mt++)
#pragma unroll
    for (int nt = 0; nt < 2; nt++) {
      int row = rowbase + wm + mt * 16 + q * 4;
      int col = wn + nt * 16 + mr;
      if (col < 44) {
#pragma unroll
        for (int r = 0; r < 4; r++)
          dbc[(long)(row + r) * 48 + col] = acc[mt][nt][r];
      }
    }
}

// ---------------- dt_proj + softplus + B/C split ----------------
__global__ void k_dtsplit(const float* __restrict__ dbc, const float* __restrict__ dtw,
                          const float* __restrict__ dtb, float* __restrict__ dt,
                          float* __restrict__ Bc, float* __restrict__ Cc) {
  int idx = blockIdx.x * 256 + threadIdx.x;
  int row = idx / 384;
  int d = idx % 384;
  const float* p = dbc + (long)row * 48;
  float acc = dtb[d];
#pragma unroll
  for (int r = 0; r < 12; r++) acc = fmaf(p[r], dtw[d * 12 + r], acc);
  float sp = (acc > 20.f) ? acc : __logf(1.f + __expf(acc));
  dt[(long)row * 384 + d] = sp;
  if (d < 16) Bc[row * 16 + d] = p[12 + d];
  else if (d < 32) Cc[row * 16 + (d - 16)] = p[28 + (d - 16)];
}

// ---------------- prep: A = -exp(A_log), rA = 1/A ----------------
__global__ void k_prep(const float* __restrict__ Alog, float* __restrict__ Aexp,
                       float* __restrict__ rAe) {
  int i = blockIdx.x * 256 + threadIdx.x;
  if (i < Din * Dst) {
    float A = -__expf(Alog[i]);
    Aexp[i] = A;
    rAe[i] = 1.f / A;
  }
}

// ---------------- scanA: per-chunk local scan, d-per-thread, h[16] in regs ----------------
__global__ __launch_bounds__(384) void k_scanA(
    const float* __restrict__ dt, const float* __restrict__ u,
    const float* __restrict__ Bc, const float* __restrict__ Aexp,
    const float* __restrict__ rAe,
    float* __restrict__ Ssum, float* __restrict__ Sdt) {
  int d = threadIdx.x;
  int c = blockIdx.x;
  int b = blockIdx.y;
  float A[16], rA[16], h[16];
  const float4* Ap4 = (const float4*)(Aexp + d * 16);
  const float4* Rp4 = (const float4*)(rAe + d * 16);
#pragma unroll
  for (int j = 0; j < 4; j++) {
    float4 av = Ap4[j], rv = Rp4[j];
    A[4 * j + 0] = av.x; A[4 * j + 1] = av.y; A[4 * j + 2] = av.z; A[4 * j + 3] = av.w;
    rA[4 * j + 0] = rv.x; rA[4 * j + 1] = rv.y; rA[4 * j + 2] = rv.z; rA[4 * j + 3] = rv.w;
  }
#pragma unroll
  for (int n = 0; n < 16; n++) h[n] = 0.f;
  float sdt = 0.f;
  long row0 = (long)b * Lseq + (long)c * CLk;
  const float* dtp = dt + row0 * 384 + d;
  const float* up  = u  + row0 * 384 + d;
  const float* Bp  = Bc + row0 * 16;
#pragma unroll 2
  for (int i = 0; i < CLk; i++) {
    float dtv = dtp[i * 384];
    float uv  = up[i * 384];
    float Bv[16];
#pragma unroll
    for (int j = 0; j < 4; j++) {
      float4 bv = *(const float4*)(Bp + i * 16 + j * 4);
      Bv[4 * j + 0] = bv.x; Bv[4 * j + 1] = bv.y; Bv[4 * j + 2] = bv.z; Bv[4 * j + 3] = bv.w;
    }
    sdt += dtv;
#pragma unroll
    for (int n = 0; n < 16; n++) {
      float a = __expf(dtv * A[n]);
      float q = rA[n] * Bv[n] * uv;
      h[n] = fmaf(a, h[n] + q, -q);
    }
  }
  long o = ((long)(b * NCk + c) * 384 + d);
  Sdt[o] = sdt;
#pragma unroll
  for (int j = 0; j < 4; j++) {
    *(float4*)(Ssum + o * 16 + j * 4) = make_float4(h[4*j], h[4*j+1], h[4*j+2], h[4*j+3]);
  }
}

// ---------------- scanB: chunk combine over NCk chunks ----------------
__global__ void k_scanB(const float* __restrict__ Ssum, const float* __restrict__ Sdt,
                        const float* __restrict__ Aexp, float* __restrict__ Hst) {
  int g = blockIdx.x * 256 + threadIdx.x;
  int n = g & 15;
  int d = (g >> 4) % 384;
  int b = g / (384 * 16);
  float A = Aexp[d * 16 + n];
  float h = 0.f;
  for (int c = 0; c < NCk; c++) {
    long o = ((long)(b * NCk + c) * 384 + d);
    float aC = __expf(A * Sdt[o]);
    Hst[o * 16 + n] = h;
    h = fmaf(aC, h, Ssum[o * 16 + n]);
  }
}

// ---------------- scanC: replay with init state, y=<h,C>, gate, emit y bf16 hi/lo ----------------
__global__ __launch_bounds__(384) void k_scanC(
    const float* __restrict__ dt, const float* __restrict__ u,
    const float* __restrict__ Bc, const float* __restrict__ Cc,
    const float* __restrict__ Aexp, const float* __restrict__ rAe,
    const float* __restrict__ Hst, const float* __restrict__ Dp,
    const float* __restrict__ z, ushort_t* __restrict__ yyh,
    ushort_t* __restrict__ yyl) {
  int d = threadIdx.x;
  int c = blockIdx.x;
  int b = blockIdx.y;
  float A[16], rA[16], h[16];
  const float4* Ap4 = (const float4*)(Aexp + d * 16);
  const float4* Rp4 = (const float4*)(rAe + d * 16);
#pragma unroll
  for (int j = 0; j < 4; j++) {
    float4 av = Ap4[j], rv = Rp4[j];
    A[4 * j + 0] = av.x; A[4 * j + 1] = av.y; A[4 * j + 2] = av.z; A[4 * j + 3] = av.w;
    rA[4 * j + 0] = rv.x; rA[4 * j + 1] = rv.y; rA[4 * j + 2] = rv.z; rA[4 * j + 3] = rv.w;
  }
  long o = ((long)(b * NCk + c) * 384 + d);
#pragma unroll
  for (int j = 0; j < 4; j++) {
    float4 hv = *(const float4*)(Hst + o * 16 + j * 4);
    h[4 * j + 0] = hv.x; h[4 * j + 1] = hv.y; h[4 * j + 2] = hv.z; h[4 * j + 3] = hv.w;
  }
  float Dv = Dp[d];
  long row0 = (long)b * Lseq + (long)c * CLk;
  const float* dtp = dt + row0 * 384 + d;
  const float* up  = u  + row0 * 384 + d;
  const float* Bp  = Bc + row0 * 16;
  const float* Cp  = Cc + row0 * 16;
  const float* zp  = z + row0 * 384 + d;
#pragma unroll 2
  for (int i = 0; i < CLk; i++) {
    float dtv = dtp[i * 384];
    float uv  = up[i * 384];
    float zv  = zp[i * 384];
    float Bv[16], Cv[16];
#pragma unroll
    for (int j = 0; j < 4; j++) {
      float4 bv = *(const float4*)(Bp + i * 16 + j * 4);
      float4 cv = *(const float4*)(Cp + i * 16 + j * 4);
      Bv[4 * j + 0] = bv.x; Bv[4 * j + 1] = bv.y; Bv[4 * j + 2] = bv.z; Bv[4 * j + 3] = bv.w;
      Cv[4 * j + 0] = cv.x; Cv[4 * j + 1] = cv.y; Cv[4 * j + 2] = cv.z; Cv[4 * j + 3] = cv.w;
    }
    float yacc = 0.f;
#pragma unroll
    for (int n = 0; n < 16; n++) {
      float a = __expf(dtv * A[n]);
      float q = rA[n] * Bv[n] * uv;
      h[n] = fmaf(a, h[n] + q, -q);
      yacc = fmaf(h[n], Cv[n], yacc);
    }
    float sil = zv / (1.f + __expf(-zv));
    float yv = (yacc + uv * Dv) * sil;
    unsigned int hb = f2bf(yv);
    yyh[row0 * 384 + i * 384 + d] = (ushort_t)hb;
    yyl[row0 * 384 + i * 384 + d] = (ushort_t)f2bf(yv - bf2f(hb));
  }
}

// ---------------- out_proj (MFMA) with LDS transpose epilogue ----------------
__global__ __launch_bounds__(256) void k_outproj_mfma(
    const ushort_t* __restrict__ Ah, const ushort_t* __restrict__ Al,
    const ushort_t* __restrict__ Bh, const ushort_t* __restrict__ Bl,
    float* __restrict__ out) {
  __shared__ __align__(16) ushort_t smem[4 * 64 * KP];
  ushort_t* sAh = smem;
  ushort_t* sAl = smem + 64 * KP;
  ushort_t* sBh = smem + 2 * 64 * KP;
  ushort_t* sBl = smem + 3 * 64 * KP;
  float* sC = (float*)smem;
  int t = threadIdx.x;
  int rowbase = blockIdx.x * 64;
  int nbase = blockIdx.y * 64;
  int lane = t & 63, w = t >> 6;
  int wm = (w & 1) * 32, wn = (w >> 1) * 32;
  int q = lane >> 4, mr = lane & 15;
  f4v acc[2][2];
#pragma unroll
  for (int i = 0; i < 2; i++)
#pragma unroll
    for (int j = 0; j < 2; j++) acc[i][j] = (f4v){0.f, 0.f, 0.f, 0.f};
  mfma_gemm64<384, 192>(Ah, Al, rowbase, Bh, Bl, nbase, sAh, sAl, sBh, sBl, acc);
  __syncthreads();
#pragma unroll
  for (int mt = 0; mt < 2; mt++)
#pragma unroll
    for (int nt = 0; nt < 2; nt++) {
      int rloc = wm + mt * 16 + q * 4;
      int cloc = wn + nt * 16 + mr;
#pragma unroll
      for (int r = 0; r < 4; r++)
        sC[(rloc + r) * 68 + cloc] = acc[mt][nt][r];
    }
  __syncthreads();
  int b = rowbase >> 12;
  int l0 = rowbase & 4095;
  int o = t >> 2;
  int lg = (t & 3) * 16;
  long obase = ((long)(b * 192 + nbase + o)) * Lseq + l0 + lg;
#pragma unroll
  for (int j4 = 0; j4 < 4; j4++) {
    float4 v = make_float4(sC[(lg + j4 * 4 + 0) * 68 + o], sC[(lg + j4 * 4 + 1) * 68 + o],
                           sC[(lg + j4 * 4 + 2) * 68 + o], sC[(lg + j4 * 4 + 3) * 68 + o]);
    *(float4*)(out + obase + j4 * 4) = v;
  }
}

extern "C" void kernel_launch(void* const* d_in, const int* in_sizes, int n_in,
                              void* d_out, int out_size, void* d_ws, size_t ws_size,
                              hipStream_t stream) {
  const float* x    = (const float*)d_in[0];
  const float* guide= (const float*)d_in[1];
  const float* gw   = (const float*)d_in[2];
  const float* ln_g = (const float*)d_in[3];
  const float* ln_b = (const float*)d_in[4];
  const float* ipw  = (const float*)d_in[5];
  const float* cw   = (const float*)d_in[6];
  const float* cb   = (const float*)d_in[7];
  const float* xpw  = (const float*)d_in[8];
  const float* dtw  = (const float*)d_in[9];
  const float* dtb  = (const float*)d_in[10];
  const float* Alog = (const float*)d_in[11];
  const float* Dp   = (const float*)d_in[12];
  const float* opw  = (const float*)d_in[13];
  float* out = (float*)d_out;
  float* ws  = (float*)d_ws;

  // Workspace (float offsets), lifetime-packed, peak 32661M... max 32662016 < proven 34340864:
  // [0,3145728):          xT[pre->guide] | uh+ul(us)[conv->xproj]
  // [0,6291456):          Ssum[scanA->scanB] | yyh+yyl(us)[scanC->outproj]
  // [3145728,6291456):    gTh+gTl(us)[pre->guide]
  // [6291456,9437184):    gxT[guide->lnT] | dbc[xproj->dtsplit]
  // [6291456,12582912):   Hst[scanB->scanC]
  // [9437184,12582912):   seqh+seql(us)[lnT->inproj]
  // [12582912,18874368):  z[inproj->scanC]
  // [18874368,25165824):  xzu[inproj->conv] | dt[dtsplit->scanC]
  // [25165824,31457280):  u[conv->scanC]
  float* xT   = ws + 0;
  ushort_t* uh   = (ushort_t*)(ws + 0);
  ushort_t* ul   = (ushort_t*)(ws + 1572864);
  float* Ssum = ws + 0;
  ushort_t* yyh  = (ushort_t*)(ws + 0);
  ushort_t* yyl  = (ushort_t*)(ws + 3145728);
  ushort_t* gTh  = (ushort_t*)(ws + 3145728);
  ushort_t* gTl  = (ushort_t*)(ws + 4718592);
  float* gxT  = ws + 6291456;
  float* dbc  = ws + 6291456;
  float* Hst  = ws + 6291456;
  ushort_t* seqh = (ushort_t*)(ws + 9437184);
  ushort_t* seql = (ushort_t*)(ws + 11010048);
  float* z    = ws + 12582912;
  float* xzu  = ws + 18874368;
  float* dt   = ws + 18874368;
  float* u    = ws + 25165824;
  float* Bc_  = ws + 31457280;  // 262144
  float* Cc_  = ws + 31719424;  // 262144
  float* Sdt  = ws + 31981568;  // 393216
  float* Aexp = ws + 32374784;  // 6144
  float* rAe  = ws + 32380928;  // 6144
  ushort_t* wsplit = (ushort_t*)(ws + 32387072);   // 549888 us = 274944 f -> end 32662016
  ushort_t* gwh = wsplit;
  ushort_t* gwl = wsplit + 36864;
  ushort_t* iwh = wsplit + 73728;
  ushort_t* iwl = wsplit + 221184;
  ushort_t* xwh = wsplit + 368640;
  ushort_t* xwl = wsplit + 385536;
  ushort_t* opwh = wsplit + 402432;
  ushort_t* opwl = wsplit + 476160;

  k_prep    <<<24,               256, 0, stream>>>(Alog, Aexp, rAe);
  k_wsplit4 <<<1074,             256, 0, stream>>>(gw, ipw, xpw, opw, wsplit);
  k_pre     <<<dim3(64, 3, 4),   256, 0, stream>>>(x, guide, xT, gTh, gTl);
  k_guide_mfma<<<dim3(256, 3),   256, 0, stream>>>(gTh, gTl, gwh, gwl, xT, gxT);
  k_lnT     <<<4096,             256, 0, stream>>>(gxT, ln_g, ln_b, seqh, seql);
  k_inproj_mfma<<<dim3(256, 12), 256, 0, stream>>>(seqh, seql, iwh, iwl, xzu, z);
  k_conv    <<<24576,            256, 0, stream>>>(xzu, cw, cb, u, uh, ul);
  k_xproj_mfma<<<256,            256, 0, stream>>>(uh, ul, xwh, xwl, dbc);
  k_dtsplit <<<24576,            256, 0, stream>>>(dbc, dtw, dtb, dt, Bc_, Cc_);
  k_scanA   <<<dim3(NCk, Bsz),   384, 0, stream>>>(dt, u, Bc_, Aexp, rAe, Ssum, Sdt);
  k_scanB   <<<96,               256, 0, stream>>>(Ssum, Sdt, Aexp, Hst);
  k_scanC   <<<dim3(NCk, Bsz),   384, 0, stream>>>(dt, u, Bc_, Cc_, Aexp, rAe, Hst, Dp, z, yyh, yyl);
  k_outproj_mfma<<<dim3(256, 3), 256, 0, stream>>>(yyh, yyl, opwh, opwl, out);
}